// Round 10
// baseline (171.442 us; speedup 1.0000x reference)
//
#include <hip/hip_runtime.h>
#include <stdint.h>

typedef unsigned short u16;
typedef __attribute__((ext_vector_type(8))) short bfrag;   // 8 x bf16 (4 VGPRs)
typedef __attribute__((ext_vector_type(4))) short bfrag4;  // 4 x bf16 (2 VGPRs)
typedef __attribute__((ext_vector_type(4))) float f32x4;   // MFMA C/D

#define MFMA_BF16 __builtin_amdgcn_mfma_f32_16x16x32_bf16

static constexpr int Bc = 2;      // batch
static constexpr int Tc = 2048;   // seq
static constexpr int Cc = 1024;   // channels
static constexpr int Hc = 16;     // heads
static constexpr int Dc = 64;     // head dim
static constexpr int N3 = 3 * Cc; // 3072, packed QKV row length

__device__ __forceinline__ u16 f2bf(float f) {
    union { unsigned int i; float f; } v; v.f = f;
    unsigned int u = v.i;
    u += 0x7fffu + ((u >> 16) & 1u);   // round-to-nearest-even
    return (u16)(u >> 16);
}
__device__ __forceinline__ unsigned int fbits(float f) {
    union { unsigned int i; float f; } v; v.f = f; return v.i;
}
// pack two f32 -> two bf16 (truncation) in ONE v_perm_b32: {hi.bf16, lo.bf16}
__device__ __forceinline__ unsigned int pack_bf2(float hi, float lo) {
    return __builtin_amdgcn_perm(fbits(hi), fbits(lo), 0x07060302u);
}

// K=16 MFMA for PV (S^T C-layout == B-operand layout)
#if __has_builtin(__builtin_amdgcn_mfma_f32_16x16x16bf16_1k)
__device__ __forceinline__ f32x4 MFMA16(bfrag4 a, bfrag4 b, f32x4 c) {
    return __builtin_amdgcn_mfma_f32_16x16x16bf16_1k(a, b, c, 0, 0, 0);
}
#elif __has_builtin(__builtin_amdgcn_mfma_f32_16x16x16_bf16)
__device__ __forceinline__ f32x4 MFMA16(bfrag4 a, bfrag4 b, f32x4 c) {
    return __builtin_amdgcn_mfma_f32_16x16x16_bf16(a, b, c, 0, 0, 0);
}
#else
__device__ __forceinline__ f32x4 MFMA16(bfrag4 a, bfrag4 b, f32x4 c) {
    bfrag a8 = {a[0], a[1], a[2], a[3], 0, 0, 0, 0};
    bfrag b8 = {b[0], b[1], b[2], b[3], 0, 0, 0, 0};
    return MFMA_BF16(a8, b8, c, 0, 0, 0);
}
#endif

// async global -> LDS, 16B per lane; deposits at lds + lane*16.
__device__ __forceinline__ void async_load16(const u16* g, u16* lds) {
    __builtin_amdgcn_global_load_lds(
        (const __attribute__((address_space(1))) unsigned int*)g,
        (__attribute__((address_space(3))) unsigned int*)lds, 16, 0, 0);
}

// ---------------------------------------------------------------------------
// Fused prep: blocks [0,4096) cvt x->bf16; [4096,7168) w_qkv T; [7168,8192) w_out T
// ---------------------------------------------------------------------------
__global__ __launch_bounds__(256) void prep(
    const float* __restrict__ x, const float* __restrict__ w_qkv,
    const float* __restrict__ w_out, u16* __restrict__ xb,
    u16* __restrict__ WqkvT, u16* __restrict__ WoutT) {
    __shared__ u16 tile[32][33];
    const int blk = blockIdx.x, tid = threadIdx.x;
    if (blk < 4096) {
        const int i = (blk * 256 + tid) * 4;
        const float4 v = *(const float4*)(x + i);
        ushort4 o;
        o.x = f2bf(v.x); o.y = f2bf(v.y); o.z = f2bf(v.z); o.w = f2bf(v.w);
        *(ushort4*)(xb + i) = o;
        return;
    }
    const float* in; u16* out; int rows, cols, c0, r0;
    if (blk < 4096 + 3072) {
        const int t = blk - 4096;            // grid (96, 32)
        in = w_qkv; out = WqkvT; rows = 1024; cols = 3072;
        c0 = (t % 96) * 32; r0 = (t / 96) * 32;
    } else {
        const int t = blk - 7168;            // grid (32, 32)
        in = w_out; out = WoutT; rows = 1024; cols = 1024;
        c0 = (t & 31) * 32; r0 = (t >> 5) * 32;
    }
    // load 32x32 fp32 tile with float4, store transposed into LDS
    const int row = tid >> 3;                // 0..31
    const int cg  = (tid & 7) * 4;           // 0,4,...,28
    const float4 v = *(const float4*)(in + (size_t)(r0 + row) * cols + c0 + cg);
    tile[cg + 0][row] = f2bf(v.x);
    tile[cg + 1][row] = f2bf(v.y);
    tile[cg + 2][row] = f2bf(v.z);
    tile[cg + 3][row] = f2bf(v.w);
    __syncthreads();
    const int tx = tid & 31, ty = tid >> 5;  // 32 x 8
    for (int i = 0; i < 4; i++)
        out[(size_t)(c0 + ty + 8 * i) * rows + r0 + tx] = tile[ty + 8 * i][tx];
}

// ---------------------------------------------------------------------------
// QKV GEMM v5 — BK=64: 2 barrier events and 48 MFMA/wave per K-step (vs 4
// events / 24 MFMA at BK=32). 128(M) x 192(N) block, 512 thr = 8 waves
// (2M x 4N), wave tile 64x48. 3-buffer ring = 120 KiB (1 block/CU), grid
// (16,32) = 512 = 2 clean passes. Per wave per half: 5 x 1KB staging windows
// (A:2, B:3), 10 x ds_read_b128, 48 MFMA.
//   Schedule/half h: vmcnt(5) certify h [wait-THEN-barrier; h's loads were
//   issued 2 halves back] -> barrier -> STAGE(h+2) -> ds_read -> lgkmcnt(0)
//   -> MFMA -> barrier. Tail: vmcnt(0) at h=15 only.
//   Hazards: STAGE(h+2) overwrites buf (h-1)%3 whose readers passed the
//   previous end-barrier; each wave certifies its own 5 loads pre-barrier.
//   LDS rows are 64 elems (128B); XOR-chunk swizzle (attn-verified):
//   stored[r][c] = global[r][c ^ (r&7)], staged via pre-swizzled source;
//   frag read chunk pk = (c ^ (l16&7))*8.
//   V-transpose fused in epilogue; Q pre-scaled by 1/8.
// ---------------------------------------------------------------------------
__global__ __launch_bounds__(512, 1) void gemm_qkv(
    const u16* __restrict__ A, const u16* __restrict__ BT,
    const float* __restrict__ bias, u16* __restrict__ outQK,
    u16* __restrict__ Vt) {
    constexpr int Kd = 1024, Nn = 3072, Td = 16;   // K, N, K/64
    extern __shared__ __align__(16) u16 smem[];
    u16* As = smem;                       // [3][128*64]
    u16* Bs = smem + 3 * (128 * 64);      // [3][192*64]

    const int tid  = threadIdx.x;
    const int wave = tid >> 6, lane = tid & 63;   // 8 waves
    const int quad = lane >> 4, l16 = lane & 15;
    const int wm = wave >> 2, wn = wave & 3;      // 2M x 4N
    const int m0 = blockIdx.y * 128, n0 = blockIdx.x * 192;

    f32x4 acc[4][3];
    #pragma unroll
    for (int i = 0; i < 4; i++)
        #pragma unroll
        for (int j = 0; j < 3; j++)
            acc[i][j] = (f32x4){0.f, 0.f, 0.f, 0.f};

    // staging lane geometry: window = 8 rows x 128B (1 KB / wave-instr).
    // lane L -> row r8 = L>>3, stored chunk (L&7) holds global chunk (L&7)^r8.
    const int r8   = lane >> 3;                   // 0..7
    const int cswz = ((lane & 7) ^ r8) * 8;       // pre-swizzled global elems

    const u16* Ag = A  + (size_t)(m0 + wave * 16 + r8) * Kd + cswz;  // 2 windows
    const u16* Bg = BT + (size_t)(n0 + wave * 24 + r8) * Kd + cswz;  // 3 windows
    u16* ldsA = As + (wave * 16) * 64;
    u16* ldsB = Bs + (wave * 24) * 64;

    // fragment-read chunk un-swizzle (row&7 == l16&7 for all frag rows)
    const int pk0 = ((quad)     ^ (l16 & 7)) * 8;   // k in [0,32)
    const int pk1 = ((quad + 4) ^ (l16 & 7)) * 8;   // k in [32,64)
    int offA[4], offB[3];
    #pragma unroll
    for (int mt = 0; mt < 4; mt++)
        offA[mt] = (wm * 64 + mt * 16 + l16) * 64;
    #pragma unroll
    for (int nt = 0; nt < 3; nt++)
        offB[nt] = (wn * 48 + nt * 16 + l16) * 64;

    #define GLD_A(h, bsel, j)                                                  \
        async_load16(Ag + (size_t)((j) * 8) * Kd + ((h) << 6),                 \
                     ldsA + (bsel) * (128 * 64) + (j) * (8 * 64));
    #define GLD_B(h, bsel, j)                                                  \
        async_load16(Bg + (size_t)((j) * 8) * Kd + ((h) << 6),                 \
                     ldsB + (bsel) * (192 * 64) + (j) * (8 * 64));
    #define STAGE_H(h, bsel)                                                   \
        { GLD_A(h, bsel, 0); GLD_A(h, bsel, 1);                                \
          GLD_B(h, bsel, 0); GLD_B(h, bsel, 1); GLD_B(h, bsel, 2); }

    // prologue: stage halves 0,1
    STAGE_H(0, 0);
    STAGE_H(1, 1);

    for (int h = 0; h < Td; h++) {
        // certify half h (own 5 loads issued 2 halves back; outstanding newer
        // = half h+1's 5, staged during h-1) — wait-THEN-barrier.
        if (h <= Td - 2) asm volatile("s_waitcnt vmcnt(5)" ::: "memory");
        else             asm volatile("s_waitcnt vmcnt(0)" ::: "memory");
        __builtin_amdgcn_s_barrier();
        asm volatile("" ::: "memory");
        if (h + 2 < Td) { STAGE_H(h + 2, (h + 2) % 3); }

        const u16* Ab = As + (h % 3) * (128 * 64);
        const u16* Bb = Bs + (h % 3) * (192 * 64);
        bfrag af0[4], af1[4], bf0[3], bf1[3];
        #pragma unroll
        for (int mt = 0; mt < 4; mt++) {
            af0[mt] = *(const bfrag*)(Ab + offA[mt] + pk0);
            af1[mt] = *(const bfrag*)(Ab + offA[mt] + pk1);
        }
        #pragma unroll
        for (int nt = 0; nt < 3; nt++) {
            bf0[nt] = *(const bfrag*)(Bb + offB[nt] + pk0);
            bf1[nt] = *(const bfrag*)(Bb + offB[nt] + pk1);
        }
        asm volatile("s_waitcnt lgkmcnt(0)" ::: "memory");
        __builtin_amdgcn_sched_barrier(0);
        __builtin_amdgcn_s_setprio(1);
        #pragma unroll
        for (int mt = 0; mt < 4; mt++)
            #pragma unroll
            for (int nt = 0; nt < 3; nt++)
                acc[mt][nt] = MFMA_BF16(af0[mt], bf0[nt], acc[mt][nt], 0, 0, 0);
        #pragma unroll
        for (int mt = 0; mt < 4; mt++)
            #pragma unroll
            for (int nt = 0; nt < 3; nt++)
                acc[mt][nt] = MFMA_BF16(af1[mt], bf1[nt], acc[mt][nt], 0, 0, 0);
        __builtin_amdgcn_s_setprio(0);
        __builtin_amdgcn_s_barrier();
        asm volatile("" ::: "memory");
    }
    #undef GLD_A
    #undef GLD_B
    #undef STAGE_H

    // epilogue: Q (scaled 1/8), K -> QKVp rows; V -> Vt[bh][d][t] (fused T).
    #pragma unroll
    for (int nt = 0; nt < 3; nt++) {
        const int gn = n0 + wn * 48 + nt * 16 + l16;
        const float bv = bias[gn];
        if (gn < 2 * Cc) {
            const float scl = (gn < Cc) ? 0.125f : 1.0f;   // uniform per nt-group
            #pragma unroll
            for (int mt = 0; mt < 4; mt++) {
                #pragma unroll
                for (int r = 0; r < 4; r++) {
                    const int gm = m0 + wm * 64 + mt * 16 + quad * 4 + r;
                    outQK[(size_t)gm * Nn + gn] = f2bf((acc[mt][nt][r] + bv) * scl);
                }
            }
        } else {
            const int gnv = gn - 2 * Cc;               // 0..1023
            const int h = gnv >> 6, d = gnv & 63;
            #pragma unroll
            for (int mt = 0; mt < 4; mt++) {
                const int gmb = m0 + wm * 64 + mt * 16 + quad * 4;
                const int b = gmb >> 11, trow = gmb & (Tc - 1);
                ushort4 o;
                o.x = f2bf(acc[mt][nt][0] + bv);
                o.y = f2bf(acc[mt][nt][1] + bv);
                o.z = f2bf(acc[mt][nt][2] + bv);
                o.w = f2bf(acc[mt][nt][3] + bv);
                *(ushort4*)(Vt + ((size_t)((b * Hc + h) * Dc + d)) * Tc + trow) = o;
            }
        }
    }
}

// ---------------------------------------------------------------------------
// Out-projection GEMM — counted-vmcnt 3-buffer schedule, BN=128. (unchanged)
// ---------------------------------------------------------------------------
__global__ __launch_bounds__(512, 2) void gemm_out(
    const u16* __restrict__ A, const u16* __restrict__ BT,
    const float* __restrict__ bias, float* __restrict__ out,
    int M, int Nn, int K) {
    extern __shared__ __align__(16) u16 smem[];
    u16* As = smem;                       // [3][128*32]
    u16* Bs = smem + 3 * (128 * 32);      // [3][128*32]

    const int tid  = threadIdx.x;
    const int wave = tid >> 6, lane = tid & 63;
    const int quad = lane >> 4, l16 = lane & 15;
    const int wm = wave >> 2, wn = wave & 3;          // 2M x 4N
    const int m0 = blockIdx.y * 128, n0 = blockIdx.x * 128;

    f32x4 acc[4][2];
    #pragma unroll
    for (int i = 0; i < 4; i++)
        #pragma unroll
        for (int j = 0; j < 2; j++)
            acc[i][j] = (f32x4){0.f, 0.f, 0.f, 0.f};

    const int rA = lane >> 2;
    const int cA = ((lane & 3) ^ (rA & 3)) * 8;

    const u16* Ag = A  + (size_t)(m0 + wave * 16 + rA) * K + cA;  // 1 instr
    const u16* Bg = BT + (size_t)(n0 + wave * 16 + rA) * K + cA;  // 1 instr
    u16* ldsA = As + (wave * 16) * 32;
    u16* ldsB = Bs + (wave * 16) * 32;

    const int swz8 = (quad ^ (l16 & 3)) * 8;
    int offA[4], offB[2];
    #pragma unroll
    for (int mt = 0; mt < 4; mt++)
        offA[mt] = (wm * 64 + mt * 16 + l16) * 32 + swz8;
    #pragma unroll
    for (int nt = 0; nt < 2; nt++)
        offB[nt] = (wn * 32 + nt * 16 + l16) * 32 + swz8;

    #define STAGE_O(t, bsel)                                                   \
        {                                                                      \
            const int k0_ = (t) << 5;                                          \
            async_load16(Ag + k0_, ldsA + (bsel) * (128 * 32));                \
            async_load16(Bg + k0_, ldsB + (bsel) * (128 * 32));                \
        }

    STAGE_O(0, 0);
    STAGE_O(1, 1);

    const int T = K >> 5;   // 32
    for (int t = 0; t < T; t++) {
        if (t + 1 < T) asm volatile("s_waitcnt vmcnt(2)" ::: "memory");
        else           asm volatile("s_waitcnt vmcnt(0)" ::: "memory");
        __builtin_amdgcn_s_barrier();
        asm volatile("" ::: "memory");
        if (t + 2 < T) { STAGE_O(t + 2, (t + 2) % 3); }

        const u16* Ab = As + (t % 3) * (128 * 32);
        const u16* Bb = Bs + (t % 3) * (128 * 32);
        bfrag af[4], bf[2];
        #pragma unroll
        for (int mt = 0; mt < 4; mt++) af[mt] = *(const bfrag*)(Ab + offA[mt]);
        #pragma unroll
        for (int nt = 0; nt < 2; nt++) bf[nt] = *(const bfrag*)(Bb + offB[nt]);

        __builtin_amdgcn_s_setprio(1);
        #pragma unroll
        for (int mt = 0; mt < 4; mt++)
            #pragma unroll
            for (int nt = 0; nt < 2; nt++)
                acc[mt][nt] = MFMA_BF16(af[mt], bf[nt], acc[mt][nt], 0, 0, 0);
        __builtin_amdgcn_s_setprio(0);
    }
    #undef STAGE_O

    #pragma unroll
    for (int nt = 0; nt < 2; nt++) {
        const int gn = n0 + wn * 32 + nt * 16 + l16;
        const float bv = bias[gn];
        #pragma unroll
        for (int mt = 0; mt < 4; mt++) {
            #pragma unroll
            for (int r = 0; r < 4; r++) {
                const int gm = m0 + wm * 64 + mt * 16 + quad * 4 + r;
                out[(size_t)gm * Nn + gn] = acc[mt][nt][r] + bv;
            }
        }
    }
}

// ---------------------------------------------------------------------------
// Causal flash attention — KEY-SLICED waves (unchanged from round 8).
// ---------------------------------------------------------------------------
__global__ __launch_bounds__(256, 3) void attn_kernel(
    const u16* __restrict__ QKVp, const u16* __restrict__ Vt,
    u16* __restrict__ Ob) {
    __shared__ __align__(16) u16 KsF[2][64 * 64];   // [key][d-chunk-swizzled]
    __shared__ __align__(16) u16 VsF[2][64 * 64];   // [d][key-chunk-swizzled]

    const int tid  = threadIdx.x;
    const int wave = tid >> 6, lane = tid & 63;
    const int quad = lane >> 4, l16 = lane & 15;

    const int bh = blockIdx.x & 31;               // same-XCD head grouping
    const int g5 = blockIdx.x >> 5;               // dispatch round 0..31
    const int jq = (g5 < 8) ? 31 - g5
                 : (g5 < 16) ? g5 + 8
                 : (g5 < 24) ? 31 - g5
                 : g5 - 24;                       // balanced, longest-first
    const int b = bh >> 4, h = bh & 15;
    const u16* Qp = QKVp + (size_t)b * Tc * N3 + h * Dc;   // row t: + t*N3
    const u16* Kp = Qp + Cc;
    const u16* Vp = Vt + (size_t)bh * Dc * Tc;

    const int row8 = lane >> 3;
    const int swz  = ((lane & 7) ^ row8) * 8;
    const int pk0 = ((quad)     ^ (l16 & 7)) * 8;
    const int pk1 = ((quad + 4) ^ (l16 & 7)) * 8;
    // V column pick for this wave's key slice (g -> wave in the r5 formula)
    const int vc = ((2 * wave + (quad >> 1)) ^ (l16 & 7)) * 8 + (quad & 1) * 4;

    // Q fragments for ALL 4 q-groups (q rows jq*64 + qg*16 + l16)
    bfrag qf0[4], qf1[4];
    #pragma unroll
    for (int qg = 0; qg < 4; qg++) {
        const u16* qp = Qp + (size_t)(jq * 64 + qg * 16 + l16) * N3 + quad * 8;
        qf0[qg] = *(const bfrag*)qp;
        qf1[qg] = *(const bfrag*)(qp + 32);
    }

    float l4[4] = {0.f, 0.f, 0.f, 0.f};
    f32x4 oacc[4][4];                 // [qg][ng], partial over this wave's keys
    #pragma unroll
    for (int qg = 0; qg < 4; qg++)
        #pragma unroll
        for (int ng = 0; ng < 4; ng++)
            oacc[qg][ng] = (f32x4){0.f, 0.f, 0.f, 0.f};

    #define STAGEKV(t, bsel)                                                    \
        {                                                                       \
            const int k0_ = (t) * 64;                                           \
            _Pragma("unroll")                                                   \
            for (int j = 0; j < 2; j++) {                                       \
                const int rr = wave * 16 + j * 8;                               \
                const int gr = rr + row8;                                       \
                async_load16(Kp + (size_t)(k0_ + gr) * N3 + swz,                \
                             &KsF[bsel][rr * 64]);                              \
                async_load16(Vp + (size_t)gr * Tc + k0_ + swz,                  \
                             &VsF[bsel][rr * 64]);                              \
            }                                                                   \
        }

    STAGEKV(0, 0);
    for (int t = 0; t <= jq; t++) {
        __syncthreads();                       // drains stage(t)
        if (t < jq) STAGEKV(t + 1, (t + 1) & 1);
        const u16* Kb = KsF[t & 1];
        const u16* Vb = VsF[t & 1];

        // ---- K frag for this wave's 16-key slice (read ONCE) ----
        const u16* kb = Kb + (wave * 16 + l16) * 64;
        bfrag kf0 = *(const bfrag*)(kb + pk0);
        bfrag kf1 = *(const bfrag*)(kb + pk1);

        // ---- S^T = K_slice @ Q^T for all 4 q-groups ----
        f32x4 s[4];
        __builtin_amdgcn_s_setprio(1);
        #pragma unroll
        for (int qg = 0; qg < 4; qg++) {
            f32x4 z = (f32x4){0.f, 0.f, 0.f, 0.f};
            z = MFMA_BF16(kf0, qf0[qg], z, 0, 0, 0);
            z = MFMA_BF16(kf1, qf1[qg], z, 0, 0, 0);
            s[qg] = z;   // s[qg][r] = score(q=jq*64+qg*16+l16, key=t*64+wave*16+quad*4+r)
        }
        __builtin_amdgcn_s_setprio(0);

        // ---- streaming softmax numerators (Q pre-scaled; bare exp) ----
        #pragma unroll
        for (int qg = 0; qg < 4; qg++)
            #pragma unroll
            for (int r = 0; r < 4; r++)
                s[qg][r] = __expf(s[qg][r]);
        if (t == jq) {   // diagonal tile: zero keys above the diagonal
            #pragma unroll
            for (int qg = 0; qg < 4; qg++)
                #pragma unroll
                for (int r = 0; r < 4; r++)
                    if (wave * 16 + quad * 4 + r > qg * 16 + l16) s[qg][r] = 0.f;
        }
        #pragma unroll
        for (int qg = 0; qg < 4; qg++)
            l4[qg] += s[qg][0] + s[qg][1] + s[qg][2] + s[qg][3];

        // ---- V frags for this wave's slice (read ONCE, reused 4x) ----
        bfrag4 vf[4];
        #pragma unroll
        for (int ng = 0; ng < 4; ng++)
            vf[ng] = *(const bfrag4*)(Vb + (ng * 16 + l16) * 64 + vc);

        // ---- O^T += V_slice^T @ P_slice^T for all q-groups ----
        __builtin_amdgcn_s_setprio(1);
        #pragma unroll
        for (int qg = 0; qg < 4; qg++) {
            union { unsigned int u[2]; bfrag4 v; } pf;
            pf.u[0] = pack_bf2(s[qg][1], s[qg][0]);
            pf.u[1] = pack_bf2(s[qg][3], s[qg][2]);
            #pragma unroll
            for (int ng = 0; ng < 4; ng++)
                oacc[qg][ng] = MFMA16(vf[ng], pf.v, oacc[qg][ng]);
        }
        __builtin_amdgcn_s_setprio(0);
    }
    #undef STAGEKV

    // ================= cross-wave reduction (LDS buffers now idle) =========
    __syncthreads();                           // all K/V reads complete

    // ---- l: [wave][qg][lane] f32 in VsF (4 KB) ----
    float* lred = (float*)VsF;
    #pragma unroll
    for (int qg = 0; qg < 4; qg++)
        lred[(wave * 4 + qg) * 64 + lane] = l4[qg];
    __syncthreads();
    float inv[4];
    #pragma unroll
    for (int qg = 0; qg < 4; qg++) {
        float ls = lred[(0 * 4 + qg) * 64 + lane] + lred[(1 * 4 + qg) * 64 + lane]
                 + lred[(2 * 4 + qg) * 64 + lane] + lred[(3 * 4 + qg) * 64 + lane];
        ls += __shfl_xor(ls, 16);
        ls += __shfl_xor(ls, 32);              // sum over quads
        inv[qg] = 1.f / ls;
    }

    // ---- O: per qg round, [wave][ng][lane] f32x4 in KsF (16 KB) ----
    f32x4* ored = (f32x4*)KsF;
    #pragma unroll
    for (int qg = 0; qg < 4; qg++) {
        __syncthreads();
        #pragma unroll
        for (int ng = 0; ng < 4; ng++)
            ored[(wave * 4 + ng) * 64 + lane] = oacc[qg][ng];
        __syncthreads();
        // wave w sums the d = w*16 stripe across the 4 key-slice partials
        f32x4 a0 = ored[(0 * 4 + wave) * 64 + lane];
        f32x4 a1 = ored[(1 * 4 + wave) * 64 + lane];
        f32x4 a2 = ored[(2 * 4 + wave) * 64 + lane];
        f32x4 a3 = ored[(3 * 4 + wave) * 64 + lane];
        const int q = jq * 64 + qg * 16 + l16;
        u16* orow = Ob + (size_t)(b * Tc + q) * Cc + h * Dc + wave * 16 + quad * 4;
        ushort4 o;
        o.x = f2bf((a0[0] + a1[0] + a2[0] + a3[0]) * inv[qg]);
        o.y = f2bf((a0[1] + a1[1] + a2[1] + a3[1]) * inv[qg]);
        o.z = f2bf((a0[2] + a1[2] + a2[2] + a3[2]) * inv[qg]);
        o.w = f2bf((a0[3] + a1[3] + a2[3] + a3[3]) * inv[qg]);
        *(ushort4*)orow = o;
    }
}

// ---------------------------------------------------------------------------
extern "C" void kernel_launch(void* const* d_in, const int* in_sizes, int n_in,
                              void* d_out, int out_size, void* d_ws, size_t ws_size,
                              hipStream_t stream) {
    const float* x     = (const float*)d_in[0];   // [B*T][C] fp32
    const float* w_qkv = (const float*)d_in[1];   // [C][3C] fp32
    const float* b_qkv = (const float*)d_in[2];   // [3C] fp32
    const float* w_out = (const float*)d_in[3];   // [C][C] fp32
    const float* b_out = (const float*)d_in[4];   // [C] fp32
    float* out = (float*)d_out;                   // [B*T][C] fp32
    u16* ws  = (u16*)d_ws;

    u16* xb    = ws;                               // [4096][1024] bf16 (x)
    u16* WqkvT = xb    + (size_t)4096 * 1024;      // [3072][1024]
    u16* WoutT = WqkvT + (size_t)3072 * 1024;      // [1024][1024]
    u16* QKVp  = WoutT + (size_t)1024 * 1024;      // [4096][3072] packed Q,K (V cols unused)
    u16* Vt    = QKVp  + (size_t)4096 * 3072;      // [B*H][D][T]
    u16* Ao    = xb;                               // alias: xb consumed by GEMM1

    static bool smem_set = false;
    if (!smem_set) {
        hipFuncSetAttribute(reinterpret_cast<const void*>(gemm_qkv),
                            hipFuncAttributeMaxDynamicSharedMemorySize,
                            120 * 1024);
        hipFuncSetAttribute(reinterpret_cast<const void*>(gemm_out),
                            hipFuncAttributeMaxDynamicSharedMemorySize,
                            48 * 1024);
        smem_set = true;
    }

    prep<<<8192, 256, 0, stream>>>(x, w_qkv, w_out, xb, WqkvT, WoutT);
    gemm_qkv<<<dim3(3072 / 192, 4096 / 128), 512, 120 * 1024, stream>>>(
        xb, WqkvT, b_qkv, QKVp, Vt);
    attn_kernel<<<1024, 256, 0, stream>>>(QKVp, Vt, Ao);
    gemm_out<<<dim3(1024 / 128, 4096 / 128), 512, 48 * 1024, stream>>>(
        Ao, WoutT, b_out, out, 4096, 1024, 1024);
}

// Round 11
// 168.091 us; speedup vs baseline: 1.0199x; 1.0199x over previous
//
#include <hip/hip_runtime.h>
#include <stdint.h>

typedef unsigned short u16;
typedef __attribute__((ext_vector_type(8))) short bfrag;   // 8 x bf16 (4 VGPRs)
typedef __attribute__((ext_vector_type(4))) short bfrag4;  // 4 x bf16 (2 VGPRs)
typedef __attribute__((ext_vector_type(4))) float f32x4;   // MFMA C/D

#define MFMA_BF16 __builtin_amdgcn_mfma_f32_16x16x32_bf16

static constexpr int Bc = 2;      // batch
static constexpr int Tc = 2048;   // seq
static constexpr int Cc = 1024;   // channels
static constexpr int Hc = 16;     // heads
static constexpr int Dc = 64;     // head dim
static constexpr int N3 = 3 * Cc; // 3072, packed QKV row length

__device__ __forceinline__ u16 f2bf(float f) {
    union { unsigned int i; float f; } v; v.f = f;
    unsigned int u = v.i;
    u += 0x7fffu + ((u >> 16) & 1u);   // round-to-nearest-even
    return (u16)(u >> 16);
}
__device__ __forceinline__ unsigned int fbits(float f) {
    union { unsigned int i; float f; } v; v.f = f; return v.i;
}
// pack two f32 -> two bf16 (truncation) in ONE v_perm_b32: {hi.bf16, lo.bf16}
__device__ __forceinline__ unsigned int pack_bf2(float hi, float lo) {
    return __builtin_amdgcn_perm(fbits(hi), fbits(lo), 0x07060302u);
}

// K=16 MFMA for PV (S^T C-layout == B-operand layout)
#if __has_builtin(__builtin_amdgcn_mfma_f32_16x16x16bf16_1k)
__device__ __forceinline__ f32x4 MFMA16(bfrag4 a, bfrag4 b, f32x4 c) {
    return __builtin_amdgcn_mfma_f32_16x16x16bf16_1k(a, b, c, 0, 0, 0);
}
#elif __has_builtin(__builtin_amdgcn_mfma_f32_16x16x16_bf16)
__device__ __forceinline__ f32x4 MFMA16(bfrag4 a, bfrag4 b, f32x4 c) {
    return __builtin_amdgcn_mfma_f32_16x16x16_bf16(a, b, c, 0, 0, 0);
}
#else
__device__ __forceinline__ f32x4 MFMA16(bfrag4 a, bfrag4 b, f32x4 c) {
    bfrag a8 = {a[0], a[1], a[2], a[3], 0, 0, 0, 0};
    bfrag b8 = {b[0], b[1], b[2], b[3], 0, 0, 0, 0};
    return MFMA_BF16(a8, b8, c, 0, 0, 0);
}
#endif

// async global -> LDS, 16B per lane; deposits at lds + lane*16.
__device__ __forceinline__ void async_load16(const u16* g, u16* lds) {
    __builtin_amdgcn_global_load_lds(
        (const __attribute__((address_space(1))) unsigned int*)g,
        (__attribute__((address_space(3))) unsigned int*)lds, 16, 0, 0);
}

// ---------------------------------------------------------------------------
// Fused prep: blocks [0,4096) cvt x->bf16; [4096,7168) w_qkv T; [7168,8192) w_out T
// ---------------------------------------------------------------------------
__global__ __launch_bounds__(256) void prep(
    const float* __restrict__ x, const float* __restrict__ w_qkv,
    const float* __restrict__ w_out, u16* __restrict__ xb,
    u16* __restrict__ WqkvT, u16* __restrict__ WoutT) {
    __shared__ u16 tile[32][33];
    const int blk = blockIdx.x, tid = threadIdx.x;
    if (blk < 4096) {
        const int i = (blk * 256 + tid) * 4;
        const float4 v = *(const float4*)(x + i);
        ushort4 o;
        o.x = f2bf(v.x); o.y = f2bf(v.y); o.z = f2bf(v.z); o.w = f2bf(v.w);
        *(ushort4*)(xb + i) = o;
        return;
    }
    const float* in; u16* out; int rows, cols, c0, r0;
    if (blk < 4096 + 3072) {
        const int t = blk - 4096;            // grid (96, 32)
        in = w_qkv; out = WqkvT; rows = 1024; cols = 3072;
        c0 = (t % 96) * 32; r0 = (t / 96) * 32;
    } else {
        const int t = blk - 7168;            // grid (32, 32)
        in = w_out; out = WoutT; rows = 1024; cols = 1024;
        c0 = (t & 31) * 32; r0 = (t >> 5) * 32;
    }
    // load 32x32 fp32 tile with float4, store transposed into LDS
    const int row = tid >> 3;                // 0..31
    const int cg  = (tid & 7) * 4;           // 0,4,...,28
    const float4 v = *(const float4*)(in + (size_t)(r0 + row) * cols + c0 + cg);
    tile[cg + 0][row] = f2bf(v.x);
    tile[cg + 1][row] = f2bf(v.y);
    tile[cg + 2][row] = f2bf(v.z);
    tile[cg + 3][row] = f2bf(v.w);
    __syncthreads();
    const int tx = tid & 31, ty = tid >> 5;  // 32 x 8
    for (int i = 0; i < 4; i++)
        out[(size_t)(c0 + ty + 8 * i) * rows + r0 + tx] = tile[ty + 8 * i][tx];
}

// ---------------------------------------------------------------------------
// QKV GEMM — m201-style phase schedule (round-8 best: 45-47 us measured).
//   128(M) x 384(N) block, 8 waves (2M x 4N), wave tile 64x96. BK=32,
//   4-buffer LDS ring (128 KiB), prefetch 3 halves deep; phases A/B per half.
//   Packed-row LDS swizzle (0 bank conflicts). V-transpose fused; Q x 1/8.
// ---------------------------------------------------------------------------
__global__ __launch_bounds__(512, 2) void gemm_qkv(
    const u16* __restrict__ A, const u16* __restrict__ BT,
    const float* __restrict__ bias, u16* __restrict__ outQK,
    u16* __restrict__ Vt) {
    constexpr int Kd = 1024, Nn = 3072, Td = 32;   // K, N, K/32
    extern __shared__ __align__(16) u16 smem[];
    u16* As = smem;                       // [4][128*32]
    u16* Bs = smem + 4 * (128 * 32);      // [4][384*32]

    const int tid  = threadIdx.x;
    const int wave = tid >> 6, lane = tid & 63;
    const int quad = lane >> 4, l16 = lane & 15;
    const int wm = wave >> 2, wn = wave & 3;          // 2M x 4N
    const int m0 = blockIdx.y * 128, n0 = blockIdx.x * 384;

    f32x4 acc[4][6];
    #pragma unroll
    for (int i = 0; i < 4; i++)
        #pragma unroll
        for (int j = 0; j < 6; j++)
            acc[i][j] = (f32x4){0.f, 0.f, 0.f, 0.f};

    // staging lane geometry (per 1KB wave-instr window = 16 rows x 64B):
    const int rloc = 2 * (lane >> 3) + ((lane >> 2) & 1);
    const int cg   = ((lane & 3) ^ ((lane >> 3) & 3)) * 8;
    // fragment-read un-swizzle
    const int rk   = (l16 >> 1) & 3;
    const int rodd = (l16 & 1) * 32;

    const u16* Ag = A  + (size_t)(m0 + wave * 16 + rloc) * Kd + cg;
    const u16* Bg = BT + (size_t)(n0 + wave * 48 + rloc) * Kd + cg;
    u16* ldsA = As + (wave * 16) * 32;
    u16* ldsB = Bs + (wave * 48) * 32;

    // packed-layout frag offsets (elems): (r>>1)*64 + (r&1)*32 + (quad^rk)*8
    int offA[4], offB[6];
    #pragma unroll
    for (int mt = 0; mt < 4; mt++) {
        const int r = wm * 64 + mt * 16 + l16;
        offA[mt] = (r >> 1) * 64 + rodd + (quad ^ rk) * 8;
    }
    #pragma unroll
    for (int nt = 0; nt < 6; nt++) {
        const int r = wn * 96 + nt * 16 + l16;
        offB[nt] = (r >> 1) * 64 + rodd + (quad ^ rk) * 8;
    }

    #define GLD_A(h, bsel)                                                     \
        async_load16(Ag + ((h) << 5), ldsA + (bsel) * (128 * 32));
    #define GLD_B(h, bsel, j)                                                  \
        async_load16(Bg + (size_t)((j) * 16) * Kd + ((h) << 5),                \
                     ldsB + (bsel) * (384 * 32) + (j) * (16 * 32));

    // prologue: stage halves 0,1,2 (12 loads/wave)
    #pragma unroll
    for (int h = 0; h < 3; h++) {
        GLD_A(h, h);
        GLD_B(h, h, 0); GLD_B(h, h, 1); GLD_B(h, h, 2);
    }
    asm volatile("s_waitcnt vmcnt(8)" ::: "memory");   // half 0 landed (mine)
    __builtin_amdgcn_s_barrier();                      // ...and everyone's
    asm volatile("" ::: "memory");

    for (int h = 0; h < Td; h++) {
        const int bsel = h & 3;
        const u16* Ab = As + bsel * (128 * 32);
        const u16* Bb = Bs + bsel * (384 * 32);
        const int psel = (h + 3) & 3;                  // prefetch buffer

        // ================= phase A =================
        bfrag af[4], bf0[3];
        #pragma unroll
        for (int mt = 0; mt < 4; mt++) af[mt] = *(const bfrag*)(Ab + offA[mt]);
        #pragma unroll
        for (int nt = 0; nt < 3; nt++) bf0[nt] = *(const bfrag*)(Bb + offB[nt]);
        if (h + 3 < Td) { GLD_A(h + 3, psel); GLD_B(h + 3, psel, 0); }
        __builtin_amdgcn_s_barrier();
        asm volatile("s_waitcnt lgkmcnt(0)" ::: "memory");
        __builtin_amdgcn_sched_barrier(0);
        __builtin_amdgcn_s_setprio(1);
        #pragma unroll
        for (int mt = 0; mt < 4; mt++)
            #pragma unroll
            for (int nt = 0; nt < 3; nt++)
                acc[mt][nt] = MFMA_BF16(af[mt], bf0[nt], acc[mt][nt], 0, 0, 0);
        __builtin_amdgcn_s_setprio(0);
        __builtin_amdgcn_s_barrier();
        asm volatile("" ::: "memory");

        // ================= phase B =================
        bfrag bf1[3];
        #pragma unroll
        for (int nt = 0; nt < 3; nt++)
            bf1[nt] = *(const bfrag*)(Bb + offB[nt + 3]);
        if (h + 3 < Td) { GLD_B(h + 3, psel, 1); GLD_B(h + 3, psel, 2); }
        // certify half h+1 (wait-THEN-barrier); never drains in steady state
        if (h <= Td - 4)      asm volatile("s_waitcnt vmcnt(8)" ::: "memory");
        else if (h == Td - 3) asm volatile("s_waitcnt vmcnt(4)" ::: "memory");
        else if (h == Td - 2) asm volatile("s_waitcnt vmcnt(0)" ::: "memory");
        __builtin_amdgcn_s_barrier();
        asm volatile("s_waitcnt lgkmcnt(0)" ::: "memory");
        __builtin_amdgcn_sched_barrier(0);
        __builtin_amdgcn_s_setprio(1);
        #pragma unroll
        for (int mt = 0; mt < 4; mt++)
            #pragma unroll
            for (int nt = 0; nt < 3; nt++)
                acc[mt][nt + 3] = MFMA_BF16(af[mt], bf1[nt], acc[mt][nt + 3], 0, 0, 0);
        __builtin_amdgcn_s_setprio(0);
        __builtin_amdgcn_s_barrier();
        asm volatile("" ::: "memory");
    }
    #undef GLD_A
    #undef GLD_B

    // epilogue: Q (scaled 1/8), K -> QKVp rows; V -> Vt[bh][d][t] (fused T).
    #pragma unroll
    for (int nt = 0; nt < 6; nt++) {
        const int gn = n0 + wn * 96 + nt * 16 + l16;
        const float bv = bias[gn];
        if (gn < 2 * Cc) {
            const float scl = (gn < Cc) ? 0.125f : 1.0f;   // uniform per nt-group
            #pragma unroll
            for (int mt = 0; mt < 4; mt++) {
                #pragma unroll
                for (int r = 0; r < 4; r++) {
                    const int gm = m0 + wm * 64 + mt * 16 + quad * 4 + r;
                    outQK[(size_t)gm * Nn + gn] = f2bf((acc[mt][nt][r] + bv) * scl);
                }
            }
        } else {
            const int gnv = gn - 2 * Cc;               // 0..1023
            const int h = gnv >> 6, d = gnv & 63;
            #pragma unroll
            for (int mt = 0; mt < 4; mt++) {
                const int gmb = m0 + wm * 64 + mt * 16 + quad * 4;
                const int b = gmb >> 11, trow = gmb & (Tc - 1);
                ushort4 o;
                o.x = f2bf(acc[mt][nt][0] + bv);
                o.y = f2bf(acc[mt][nt][1] + bv);
                o.z = f2bf(acc[mt][nt][2] + bv);
                o.w = f2bf(acc[mt][nt][3] + bv);
                *(ushort4*)(Vt + ((size_t)((b * Hc + h) * Dc + d)) * Tc + trow) = o;
            }
        }
    }
}

// ---------------------------------------------------------------------------
// Out-projection GEMM — counted-vmcnt 3-buffer schedule, BN=128. (unchanged)
// ---------------------------------------------------------------------------
__global__ __launch_bounds__(512, 2) void gemm_out(
    const u16* __restrict__ A, const u16* __restrict__ BT,
    const float* __restrict__ bias, float* __restrict__ out,
    int M, int Nn, int K) {
    extern __shared__ __align__(16) u16 smem[];
    u16* As = smem;                       // [3][128*32]
    u16* Bs = smem + 3 * (128 * 32);      // [3][128*32]

    const int tid  = threadIdx.x;
    const int wave = tid >> 6, lane = tid & 63;
    const int quad = lane >> 4, l16 = lane & 15;
    const int wm = wave >> 2, wn = wave & 3;          // 2M x 4N
    const int m0 = blockIdx.y * 128, n0 = blockIdx.x * 128;

    f32x4 acc[4][2];
    #pragma unroll
    for (int i = 0; i < 4; i++)
        #pragma unroll
        for (int j = 0; j < 2; j++)
            acc[i][j] = (f32x4){0.f, 0.f, 0.f, 0.f};

    const int rA = lane >> 2;
    const int cA = ((lane & 3) ^ (rA & 3)) * 8;

    const u16* Ag = A  + (size_t)(m0 + wave * 16 + rA) * K + cA;  // 1 instr
    const u16* Bg = BT + (size_t)(n0 + wave * 16 + rA) * K + cA;  // 1 instr
    u16* ldsA = As + (wave * 16) * 32;
    u16* ldsB = Bs + (wave * 16) * 32;

    const int swz8 = (quad ^ (l16 & 3)) * 8;
    int offA[4], offB[2];
    #pragma unroll
    for (int mt = 0; mt < 4; mt++)
        offA[mt] = (wm * 64 + mt * 16 + l16) * 32 + swz8;
    #pragma unroll
    for (int nt = 0; nt < 2; nt++)
        offB[nt] = (wn * 32 + nt * 16 + l16) * 32 + swz8;

    #define STAGE_O(t, bsel)                                                   \
        {                                                                      \
            const int k0_ = (t) << 5;                                          \
            async_load16(Ag + k0_, ldsA + (bsel) * (128 * 32));                \
            async_load16(Bg + k0_, ldsB + (bsel) * (128 * 32));                \
        }

    STAGE_O(0, 0);
    STAGE_O(1, 1);

    const int T = K >> 5;   // 32
    for (int t = 0; t < T; t++) {
        if (t + 1 < T) asm volatile("s_waitcnt vmcnt(2)" ::: "memory");
        else           asm volatile("s_waitcnt vmcnt(0)" ::: "memory");
        __builtin_amdgcn_s_barrier();
        asm volatile("" ::: "memory");
        if (t + 2 < T) { STAGE_O(t + 2, (t + 2) % 3); }

        const u16* Ab = As + (t % 3) * (128 * 32);
        const u16* Bb = Bs + (t % 3) * (128 * 32);
        bfrag af[4], bf[2];
        #pragma unroll
        for (int mt = 0; mt < 4; mt++) af[mt] = *(const bfrag*)(Ab + offA[mt]);
        #pragma unroll
        for (int nt = 0; nt < 2; nt++) bf[nt] = *(const bfrag*)(Bb + offB[nt]);

        __builtin_amdgcn_s_setprio(1);
        #pragma unroll
        for (int mt = 0; mt < 4; mt++)
            #pragma unroll
            for (int nt = 0; nt < 2; nt++)
                acc[mt][nt] = MFMA_BF16(af[mt], bf[nt], acc[mt][nt], 0, 0, 0);
        __builtin_amdgcn_s_setprio(0);
    }
    #undef STAGE_O

    #pragma unroll
    for (int nt = 0; nt < 2; nt++) {
        const int gn = n0 + wn * 32 + nt * 16 + l16;
        const float bv = bias[gn];
        #pragma unroll
        for (int mt = 0; mt < 4; mt++) {
            #pragma unroll
            for (int r = 0; r < 4; r++) {
                const int gm = m0 + wm * 64 + mt * 16 + quad * 4 + r;
                out[(size_t)gm * Nn + gn] = acc[mt][nt][r] + bv;
            }
        }
    }
}

// ---------------------------------------------------------------------------
// Causal flash attention — KEY-SLICED waves (round-8 winner), with the
// cross-wave O-reduction merged to 2 rounds (qg pair per round: KsF + VsF
// each hold exactly [4 waves][4 ng][64 lanes] f32x4 = 16 KB). Barrier count
// in the epilogue drops 10 -> 6.
// ---------------------------------------------------------------------------
__global__ __launch_bounds__(256, 3) void attn_kernel(
    const u16* __restrict__ QKVp, const u16* __restrict__ Vt,
    u16* __restrict__ Ob) {
    __shared__ __align__(16) u16 KsF[2][64 * 64];   // [key][d-chunk-swizzled]
    __shared__ __align__(16) u16 VsF[2][64 * 64];   // [d][key-chunk-swizzled]

    const int tid  = threadIdx.x;
    const int wave = tid >> 6, lane = tid & 63;
    const int quad = lane >> 4, l16 = lane & 15;

    const int bh = blockIdx.x & 31;               // same-XCD head grouping
    const int g5 = blockIdx.x >> 5;               // dispatch round 0..31
    const int jq = (g5 < 8) ? 31 - g5
                 : (g5 < 16) ? g5 + 8
                 : (g5 < 24) ? 31 - g5
                 : g5 - 24;                       // balanced, longest-first
    const int b = bh >> 4, h = bh & 15;
    const u16* Qp = QKVp + (size_t)b * Tc * N3 + h * Dc;   // row t: + t*N3
    const u16* Kp = Qp + Cc;
    const u16* Vp = Vt + (size_t)bh * Dc * Tc;

    const int row8 = lane >> 3;
    const int swz  = ((lane & 7) ^ row8) * 8;
    const int pk0 = ((quad)     ^ (l16 & 7)) * 8;
    const int pk1 = ((quad + 4) ^ (l16 & 7)) * 8;
    // V column pick for this wave's key slice
    const int vc = ((2 * wave + (quad >> 1)) ^ (l16 & 7)) * 8 + (quad & 1) * 4;

    // Q fragments for ALL 4 q-groups (q rows jq*64 + qg*16 + l16)
    bfrag qf0[4], qf1[4];
    #pragma unroll
    for (int qg = 0; qg < 4; qg++) {
        const u16* qp = Qp + (size_t)(jq * 64 + qg * 16 + l16) * N3 + quad * 8;
        qf0[qg] = *(const bfrag*)qp;
        qf1[qg] = *(const bfrag*)(qp + 32);
    }

    float l4[4] = {0.f, 0.f, 0.f, 0.f};
    f32x4 oacc[4][4];                 // [qg][ng], partial over this wave's keys
    #pragma unroll
    for (int qg = 0; qg < 4; qg++)
        #pragma unroll
        for (int ng = 0; ng < 4; ng++)
            oacc[qg][ng] = (f32x4){0.f, 0.f, 0.f, 0.f};

    #define STAGEKV(t, bsel)                                                    \
        {                                                                       \
            const int k0_ = (t) * 64;                                           \
            _Pragma("unroll")                                                   \
            for (int j = 0; j < 2; j++) {                                       \
                const int rr = wave * 16 + j * 8;                               \
                const int gr = rr + row8;                                       \
                async_load16(Kp + (size_t)(k0_ + gr) * N3 + swz,                \
                             &KsF[bsel][rr * 64]);                              \
                async_load16(Vp + (size_t)gr * Tc + k0_ + swz,                  \
                             &VsF[bsel][rr * 64]);                              \
            }                                                                   \
        }

    STAGEKV(0, 0);
    for (int t = 0; t <= jq; t++) {
        __syncthreads();                       // drains stage(t)
        if (t < jq) STAGEKV(t + 1, (t + 1) & 1);
        const u16* Kb = KsF[t & 1];
        const u16* Vb = VsF[t & 1];

        // ---- K frag for this wave's 16-key slice (read ONCE) ----
        const u16* kb = Kb + (wave * 16 + l16) * 64;
        bfrag kf0 = *(const bfrag*)(kb + pk0);
        bfrag kf1 = *(const bfrag*)(kb + pk1);

        // ---- S^T = K_slice @ Q^T for all 4 q-groups ----
        f32x4 s[4];
        __builtin_amdgcn_s_setprio(1);
        #pragma unroll
        for (int qg = 0; qg < 4; qg++) {
            f32x4 z = (f32x4){0.f, 0.f, 0.f, 0.f};
            z = MFMA_BF16(kf0, qf0[qg], z, 0, 0, 0);
            z = MFMA_BF16(kf1, qf1[qg], z, 0, 0, 0);
            s[qg] = z;   // score(q=jq*64+qg*16+l16, key=t*64+wave*16+quad*4+r)
        }
        __builtin_amdgcn_s_setprio(0);

        // ---- streaming softmax numerators (Q pre-scaled; bare exp) ----
        #pragma unroll
        for (int qg = 0; qg < 4; qg++)
            #pragma unroll
            for (int r = 0; r < 4; r++)
                s[qg][r] = __expf(s[qg][r]);
        if (t == jq) {   // diagonal tile: zero keys above the diagonal
            #pragma unroll
            for (int qg = 0; qg < 4; qg++)
                #pragma unroll
                for (int r = 0; r < 4; r++)
                    if (wave * 16 + quad * 4 + r > qg * 16 + l16) s[qg][r] = 0.f;
        }
        #pragma unroll
        for (int qg = 0; qg < 4; qg++)
            l4[qg] += s[qg][0] + s[qg][1] + s[qg][2] + s[qg][3];

        // ---- V frags for this wave's slice (read ONCE, reused 4x) ----
        bfrag4 vf[4];
        #pragma unroll
        for (int ng = 0; ng < 4; ng++)
            vf[ng] = *(const bfrag4*)(Vb + (ng * 16 + l16) * 64 + vc);

        // ---- O^T += V_slice^T @ P_slice^T for all q-groups ----
        __builtin_amdgcn_s_setprio(1);
        #pragma unroll
        for (int qg = 0; qg < 4; qg++) {
            union { unsigned int u[2]; bfrag4 v; } pf;
            pf.u[0] = pack_bf2(s[qg][1], s[qg][0]);
            pf.u[1] = pack_bf2(s[qg][3], s[qg][2]);
            #pragma unroll
            for (int ng = 0; ng < 4; ng++)
                oacc[qg][ng] = MFMA16(vf[ng], pf.v, oacc[qg][ng]);
        }
        __builtin_amdgcn_s_setprio(0);
    }
    #undef STAGEKV

    // ================= cross-wave reduction (LDS buffers now idle) =========
    __syncthreads();                           // all K/V reads complete

    // ---- l: [wave][qg][lane] f32 in VsF (4 KB) ----
    float* lred = (float*)VsF;
    #pragma unroll
    for (int qg = 0; qg < 4; qg++)
        lred[(wave * 4 + qg) * 64 + lane] = l4[qg];
    __syncthreads();
    float inv[4];
    #pragma unroll
    for (int qg = 0; qg < 4; qg++) {
        float ls = lred[(0 * 4 + qg) * 64 + lane] + lred[(1 * 4 + qg) * 64 + lane]
                 + lred[(2 * 4 + qg) * 64 + lane] + lred[(3 * 4 + qg) * 64 + lane];
        ls += __shfl_xor(ls, 16);
        ls += __shfl_xor(ls, 32);              // sum over quads
        inv[qg] = 1.f / ls;
    }

    // ---- O: 2 rounds, qg pair per round (KsF = even qg, VsF = odd qg) ----
    f32x4* redK = (f32x4*)KsF;                 // 1024 f32x4 = 16 KB
    f32x4* redV = (f32x4*)VsF;                 // 1024 f32x4 = 16 KB
    #pragma unroll
    for (int rr = 0; rr < 2; rr++) {
        const int qgA = 2 * rr, qgB = 2 * rr + 1;
        __syncthreads();                       // prior reads of KsF/VsF done
        #pragma unroll
        for (int ng = 0; ng < 4; ng++) {
            redK[(wave * 4 + ng) * 64 + lane] = oacc[qgA][ng];
            redV[(wave * 4 + ng) * 64 + lane] = oacc[qgB][ng];
        }
        __syncthreads();
        // wave w sums the d = w*16 stripe across the 4 key-slice partials
        f32x4 aA = redK[(0 * 4 + wave) * 64 + lane]
                 + redK[(1 * 4 + wave) * 64 + lane]
                 + redK[(2 * 4 + wave) * 64 + lane]
                 + redK[(3 * 4 + wave) * 64 + lane];
        f32x4 aB = redV[(0 * 4 + wave) * 64 + lane]
                 + redV[(1 * 4 + wave) * 64 + lane]
                 + redV[(2 * 4 + wave) * 64 + lane]
                 + redV[(3 * 4 + wave) * 64 + lane];
        const int qA = jq * 64 + qgA * 16 + l16;
        u16* orowA = Ob + (size_t)(b * Tc + qA) * Cc + h * Dc + wave * 16 + quad * 4;
        ushort4 oA;
        oA.x = f2bf(aA[0] * inv[qgA]);
        oA.y = f2bf(aA[1] * inv[qgA]);
        oA.z = f2bf(aA[2] * inv[qgA]);
        oA.w = f2bf(aA[3] * inv[qgA]);
        *(ushort4*)orowA = oA;
        u16* orowB = orowA + (size_t)16 * Cc;  // qgB = qgA + 1 -> +16 q rows
        ushort4 oB;
        oB.x = f2bf(aB[0] * inv[qgB]);
        oB.y = f2bf(aB[1] * inv[qgB]);
        oB.z = f2bf(aB[2] * inv[qgB]);
        oB.w = f2bf(aB[3] * inv[qgB]);
        *(ushort4*)orowB = oB;
    }
}

// ---------------------------------------------------------------------------
extern "C" void kernel_launch(void* const* d_in, const int* in_sizes, int n_in,
                              void* d_out, int out_size, void* d_ws, size_t ws_size,
                              hipStream_t stream) {
    const float* x     = (const float*)d_in[0];   // [B*T][C] fp32
    const float* w_qkv = (const float*)d_in[1];   // [C][3C] fp32
    const float* b_qkv = (const float*)d_in[2];   // [3C] fp32
    const float* w_out = (const float*)d_in[3];   // [C][C] fp32
    const float* b_out = (const float*)d_in[4];   // [C] fp32
    float* out = (float*)d_out;                   // [B*T][C] fp32
    u16* ws  = (u16*)d_ws;

    u16* xb    = ws;                               // [4096][1024] bf16 (x)
    u16* WqkvT = xb    + (size_t)4096 * 1024;      // [3072][1024]
    u16* WoutT = WqkvT + (size_t)3072 * 1024;      // [1024][1024]
    u16* QKVp  = WoutT + (size_t)1024 * 1024;      // [4096][3072] packed Q,K (V cols unused)
    u16* Vt    = QKVp  + (size_t)4096 * 3072;      // [B*H][D][T]
    u16* Ao    = xb;                               // alias: xb consumed by GEMM1

    static bool smem_set = false;
    if (!smem_set) {
        hipFuncSetAttribute(reinterpret_cast<const void*>(gemm_qkv),
                            hipFuncAttributeMaxDynamicSharedMemorySize,
                            128 * 1024);
        hipFuncSetAttribute(reinterpret_cast<const void*>(gemm_out),
                            hipFuncAttributeMaxDynamicSharedMemorySize,
                            48 * 1024);
        smem_set = true;
    }

    prep<<<8192, 256, 0, stream>>>(x, w_qkv, w_out, xb, WqkvT, WoutT);
    gemm_qkv<<<dim3(3072 / 384, 4096 / 128), 512, 128 * 1024, stream>>>(
        xb, WqkvT, b_qkv, QKVp, Vt);
    attn_kernel<<<1024, 256, 0, stream>>>(QKVp, Vt, Ao);
    gemm_out<<<dim3(1024 / 128, 4096 / 128), 512, 48 * 1024, stream>>>(
        Ao, WoutT, b_out, out, 4096, 1024, 1024);
}